// Round 9
// baseline (374.724 us; speedup 1.0000x reference)
//
#include <hip/hip_runtime.h>
#include <math.h>

typedef __bf16 bf16;
typedef __bf16 bf16x8 __attribute__((ext_vector_type(8)));
typedef __bf16 bf16x4 __attribute__((ext_vector_type(4)));
typedef float  f32x4  __attribute__((ext_vector_type(4)));
typedef unsigned int u32;

#define MFMA16(a, b, c) __builtin_amdgcn_mfma_f32_16x16x32_bf16((a), (b), (c), 0, 0, 0)

__device__ __forceinline__ void async_copy16(const bf16* g, bf16* l) {
  __builtin_amdgcn_global_load_lds((const __attribute__((address_space(1))) void*)g,
                                   (__attribute__((address_space(3))) void*)l, 16, 0, 0);
}

__device__ __forceinline__ float fast_exp2(float x) {
#if __has_builtin(__builtin_amdgcn_exp2f)
  return __builtin_amdgcn_exp2f(x);
#else
  float r; asm("v_exp_f32 %0, %1" : "=v"(r) : "v"(x)); return r;
#endif
}

__device__ __forceinline__ float fast_rcp(float x) {
#if __has_builtin(__builtin_amdgcn_rcpf)
  return __builtin_amdgcn_rcpf(x);
#else
  float r; asm("v_rcp_f32 %0, %1" : "=v"(r) : "v"(x)); return r;
#endif
}

// erf via Abramowitz-Stegun 7.1.26 (|err| ~5e-7, far below bf16 eps); native exp2
__device__ __forceinline__ float fast_erff(float x) {
  float ax = fabsf(x);
  float t = fast_rcp(1.0f + 0.3275911f * ax);
  float p = t * (0.254829592f + t * (-0.284496736f + t * (1.421413741f +
            t * (-1.453152027f + t * 1.061405429f))));
  float e = fast_exp2(-ax * ax * 1.4426950408889634f);
  float r = 1.0f - p * e;
  return x < 0.0f ? -r : r;
}

// ---------- LayerNorm: fp32 x -> bf16 norm. One block/token ----------
__global__ __launch_bounds__(256) void ln_kernel(const float* __restrict__ x,
    const float* __restrict__ g, const float* __restrict__ b, bf16* __restrict__ nrm) {
  const int tok = blockIdx.x, t = threadIdx.x;
  const float* xr = x + (size_t)tok * 768;
  float v0 = xr[t], v1 = xr[t + 256], v2 = xr[t + 512];
  float s = v0 + v1 + v2, ss = v0 * v0 + v1 * v1 + v2 * v2;
  for (int off = 32; off; off >>= 1) {
    s += __shfl_down(s, off, 64); ss += __shfl_down(ss, off, 64);
  }
  __shared__ float red[8];
  if ((t & 63) == 0) { red[(t >> 6) * 2] = s; red[(t >> 6) * 2 + 1] = ss; }
  __syncthreads();
  s = red[0] + red[2] + red[4] + red[6];
  ss = red[1] + red[3] + red[5] + red[7];
  float mu = s * (1.f / 768.f);
  float rstd = rsqrtf(ss * (1.f / 768.f) - mu * mu + 1e-5f);
  bf16* o = nrm + (size_t)tok * 768;
  o[t]       = (bf16)((v0 - mu) * rstd * g[t]       + b[t]);
  o[t + 256] = (bf16)((v1 - mu) * rstd * g[t + 256] + b[t + 256]);
  o[t + 512] = (bf16)((v2 - mu) * rstd * g[t + 512] + b[t + 512]);
}

// ---------- cast+transpose: Wt[n'][k] = (bf16)W[k][n]; PERM remaps qkv cols ----------
template <int PERM>
__global__ __launch_bounds__(256) void castT_kernel(const float* __restrict__ in,
    bf16* __restrict__ out, int K, int N) {
  __shared__ float tile[64][65];
  const int t = threadIdx.x;
  const int r = t >> 4, c4 = (t & 15) * 4;
  const int k0 = blockIdx.y * 64, n0 = blockIdx.x * 64;
  for (int it = 0; it < 4; ++it) {
    int row = r + it * 16;
    const float4 v = *(const float4*)(in + (size_t)(k0 + row) * N + n0 + c4);
    tile[row][c4] = v.x; tile[row][c4 + 1] = v.y;
    tile[row][c4 + 2] = v.z; tile[row][c4 + 3] = v.w;
  }
  __syncthreads();
  for (int it = 0; it < 4; ++it) {
    int row = r + it * 16;
    int n = n0 + row;
    if (PERM) {
      int which = n / 768, rem = n - which * 768;
      int d = rem / 12, h = rem - d * 12;
      n = which * 768 + h * 64 + d;
    }
    bf16x4 v;
    for (int j = 0; j < 4; ++j) v[j] = (bf16)tile[c4 + j][row];
    *(bf16x4*)(out + (size_t)n * K + k0 + c4) = v;
  }
}

// ---------- GEMM: C[M,N] = A[M,K]@Bt[N,K]^T; BK=64 (two 32-wide LDS halves) ----------
// R8: XOR-swizzled LDS sub-blocks (bank-conflict-free) + bijective XCD-chunked remap.
// R9: MLP GEMMs moved to MT=128 (64x64 per wave): LDS reads per FLOP drop 1.5x --
//     the conflict-free ds_read_b128 pipe (~12 cyc/CU each) is the longest pole.
template <int MT, int RES, int BIAS, int GELU, int OUTF32, int SPLIT>
__global__ __launch_bounds__(256) void gemm_bt(
    const bf16* __restrict__ A, const bf16* __restrict__ Bt, int ldb,
    void* __restrict__ Cv, const float* __restrict__ bias, const float* __restrict__ res,
    bf16* __restrict__ qo, bf16* __restrict__ ko, bf16* __restrict__ vo,
    int M, int N, int K) {
  constexpr int NJ = (MT == 128) ? 4 : 2;
  constexpr int AH = MT * 32;              // elements per k-half of A
  __shared__ bf16 As[2 * AH];
  __shared__ bf16 Bs[2 * 4096];
  const int t = threadIdx.x;
  const int l = t & 63, w = t >> 6;
  const int lr = l >> 4, lc = l & 15;
  const int wm = (MT == 128) ? (w >> 1) : 0;
  const int wn = (MT == 128) ? (w & 1) : w;

  // XCD-chunked remap (physical id%8 = XCD; give each XCD a contiguous tile chunk)
  const int nwg = gridDim.x * gridDim.y;
  int bid = blockIdx.y * gridDim.x + blockIdx.x;
  if ((nwg & 7) == 0) bid = (bid & 7) * (nwg >> 3) + (bid >> 3);
  const int m0 = (bid / gridDim.x) * MT, n0 = (bid % gridDim.x) * 128;

  const int srow = t >> 2;                 // 0..63
  const int scol = ((t & 3) ^ ((t >> 3) & 3)) * 8;   // XOR-swizzled source sub-block
  const int sw   = (lr ^ ((lc >> 1) & 3)) * 8;       // matching read-side XOR
  const bf16* ga0 = A + (size_t)(m0 + srow) * K + scol;
  const bf16* ga1 = A + (size_t)(m0 + 64 + srow) * K + scol;   // MT==128 only
  const bf16* gb0 = Bt + (size_t)(n0 + srow) * ldb + scol;
  const bf16* gb1 = Bt + (size_t)(n0 + 64 + srow) * ldb + scol;

  f32x4 acc[4][NJ];
  for (int i = 0; i < 4; ++i)
    for (int j = 0; j < NJ; ++j) acc[i][j] = (f32x4){0.f, 0.f, 0.f, 0.f};

  for (int k0 = 0; k0 < K; k0 += 64) {
    async_copy16(ga0 + k0,      &As[w * 512]);
    async_copy16(ga0 + k0 + 32, &As[AH + w * 512]);
    if (MT == 128) {
      async_copy16(ga1 + k0,      &As[2048 + w * 512]);
      async_copy16(ga1 + k0 + 32, &As[AH + 2048 + w * 512]);
    }
    async_copy16(gb0 + k0,      &Bs[w * 512]);
    async_copy16(gb0 + k0 + 32, &Bs[4096 + w * 512]);
    async_copy16(gb1 + k0,      &Bs[2048 + w * 512]);
    async_copy16(gb1 + k0 + 32, &Bs[4096 + 2048 + w * 512]);
    __syncthreads();
    for (int h = 0; h < 2; ++h) {
      bf16x8 af[4], bfr[NJ];
      for (int i = 0; i < 4; ++i)
        af[i] = *(const bf16x8*)&As[h * AH + (wm * 64 + i * 16 + lc) * 32 + sw];
      for (int j = 0; j < NJ; ++j)
        bfr[j] = *(const bf16x8*)&Bs[h * 4096 + (wn * 16 * NJ + j * 16 + lc) * 32 + sw];
      for (int i = 0; i < 4; ++i)
        for (int j = 0; j < NJ; ++j)
          acc[i][j] = MFMA16(af[i], bfr[j], acc[i][j]);
    }
    __syncthreads();
  }

  const size_t Ns = (size_t)N;
  for (int i = 0; i < 4; ++i) {
    int rowb = m0 + wm * 64 + i * 16 + lr * 4;
    for (int j = 0; j < NJ; ++j) {
      int col = n0 + wn * 16 * NJ + j * 16 + lc;
      float bv = BIAS ? bias[col] : 0.f;
      for (int r = 0; r < 4; ++r) {
        int row = rowb + r;
        float vv = acc[i][j][r];
        if (BIAS) vv += bv;
        if (GELU) vv = 0.5f * vv * (1.f + fast_erff(vv * 0.70710678118654752f));
        if (RES)  vv += res[(size_t)row * Ns + col];
        if (SPLIT) {
          int which = col / 768;
          int rem = col - which * 768;
          int h = rem >> 6, d = rem & 63;
          int bb = row >> 11, tt = row & 2047;
          if (which == 2) {
            // V written directly in the attn LDS image (vT fused):
            // s = perm(key), pos = ((s>>3)^(d&7))*8 + (s&7)
            int T = tt >> 6, k2 = tt & 63;
            int sv = (k2 & 32) | ((k2 & 12) << 1) | ((k2 & 16) >> 2) | (k2 & 3);
            int pos = ((((sv >> 3) ^ (d & 7)) << 3) | (sv & 7));
            vo[(size_t)(bb * 12 + h) * 131072 + (size_t)T * 4096 + d * 64 + pos] = (bf16)vv;
          } else {
            // fold softmax scale (DIM^-0.5 * log2e) into Q; f32 mul before bf16 cast
            if (which == 0) vv *= 0.18033688011112042f;
            bf16* dst = which == 0 ? qo : ko;
            dst[((size_t)((bb * 12 + h) * 2048 + tt)) * 64 + d] = (bf16)vv;
          }
        } else if (OUTF32) {
          ((float*)Cv)[(size_t)row * Ns + col] = vv;
        } else {
          ((bf16*)Cv)[(size_t)row * Ns + col] = (bf16)vv;
        }
      }
    }
  }
}

// ---------- Flash attention v10: 4 waves x 32 q-rows -> 3 waves/SIMD -------------
// (proven R7) dbuf + counted vmcnt + native exp2 + folded scale + pre-transposed V
// + XCD swizzle + 768-block even grid; 3072 waves = 3 waves/SIMD.
__global__ __launch_bounds__(256) void attn_kernel(const bf16* __restrict__ q,
    const bf16* __restrict__ k, const bf16* __restrict__ v, bf16* __restrict__ out) {
  __shared__ bf16 Ks0[4096], Ks1[4096], Vs0[4096], Vs1[4096];  // 32 KB
  const int t = threadIdx.x;
  const int l = t & 63, w = t >> 6;                            // w in {0..3}
  const int g = l >> 4, c = l & 15;
  const int id = blockIdx.y * 16 + blockIdx.x;
  const int swz = (id & 7) * 96 + (id >> 3);
  const int bh = swz >> 4;
  const int q0 = (swz & 15) * 128;
  const size_t base = (size_t)bh * (2048 * 64);
  const int qr = q0 + w * 32;
  bf16x8 aq[2][2];
  for (int rt = 0; rt < 2; ++rt) {
    aq[rt][0] = *(const bf16x8*)(q + base + (size_t)(qr + rt * 16 + c) * 64 + 8 * g);
    aq[rt][1] = *(const bf16x8*)(q + base + (size_t)(qr + rt * 16 + c) * 64 + 32 + 8 * g);
  }
  f32x4 O[2][4], O5[2];
  for (int rt = 0; rt < 2; ++rt) {
    for (int j = 0; j < 4; ++j) O[rt][j] = (f32x4){0.f, 0.f, 0.f, 0.f};
    O5[rt] = (f32x4){0.f, 0.f, 0.f, 0.f};
  }
  bf16x8 ones;
  for (int i = 0; i < 8; ++i) ones[i] = (bf16)1.0f;

  const bf16* kt = k + base + (size_t)(8 * w + (l >> 3)) * 64 + ((l & 7) ^ (l >> 3)) * 8;
  const bf16* vt = v + base + w * 512 + l * 8;
  const int pk0 = (g ^ (c & 7)) * 8;
  const int pk1 = ((4 + g) ^ (c & 7)) * 8;

  auto stage = [&](const bf16* kp, const bf16* vp, bf16* KsD, bf16* VsD) {
    async_copy16(kp,        KsD + w * 512);
    async_copy16(kp + 2048, KsD + 2048 + w * 512);
    async_copy16(vp,        VsD + w * 512);
    async_copy16(vp + 2048, VsD + 2048 + w * 512);
  };

  auto compute = [&](const bf16* KsP, const bf16* VsP) {
    bf16x8 ap[2][2];
    #pragma unroll
    for (int m = 0; m < 4; ++m) {
      bf16x8 b0 = *(const bf16x8*)&KsP[(16 * m + c) * 64 + pk0];
      bf16x8 b1 = *(const bf16x8*)&KsP[(16 * m + c) * 64 + pk1];
      f32x4 Sm[2];
      #pragma unroll
      for (int rt = 0; rt < 2; ++rt) {
        f32x4 z = (f32x4){0.f, 0.f, 0.f, 0.f};
        z = MFMA16(b0, aq[rt][0], z);
        Sm[rt] = MFMA16(b1, aq[rt][1], z);
      }
      #pragma unroll
      for (int rt = 0; rt < 2; ++rt)
        #pragma unroll
        for (int r = 0; r < 4; ++r)
          ap[rt][m >> 1][(m & 1) * 4 + r] = (bf16)fast_exp2(Sm[rt][r]);
    }
    #pragma unroll
    for (int j = 0; j < 4; ++j) {
      bf16x8 bv0 = *(const bf16x8*)&VsP[(16 * j + c) * 64 + pk0];
      bf16x8 bv1 = *(const bf16x8*)&VsP[(16 * j + c) * 64 + pk1];
      #pragma unroll
      for (int rt = 0; rt < 2; ++rt) {
        O[rt][j] = MFMA16(ap[rt][0], bv0, O[rt][j]);
        O[rt][j] = MFMA16(ap[rt][1], bv1, O[rt][j]);
      }
    }
    #pragma unroll
    for (int rt = 0; rt < 2; ++rt) {
      O5[rt] = MFMA16(ap[rt][0], ones, O5[rt]);
      O5[rt] = MFMA16(ap[rt][1], ones, O5[rt]);
    }
  };

  stage(kt, vt, Ks0, Vs0);
  kt += 4096; vt += 4096;
  bf16 *ka = Ks0, *kb = Ks1, *va = Vs0, *vb = Vs1;
  for (int i = 0; i < 32; ++i) {
    __builtin_amdgcn_s_barrier();          // all waves done reading the other buffer
    if (i + 1 < 32) {
      stage(kt, vt, kb, vb);               // issue next tile (4 loads stay in flight)
      kt += 4096; vt += 4096;
      asm volatile("s_waitcnt vmcnt(4)" ::: "memory");   // current tile's loads done
    } else {
      asm volatile("s_waitcnt vmcnt(0)" ::: "memory");
    }
    __builtin_amdgcn_sched_barrier(0);
    __builtin_amdgcn_s_barrier();          // global visibility of current tile
    compute(ka, va);
    bf16* tmp;
    tmp = ka; ka = kb; kb = tmp;
    tmp = va; va = vb; vb = tmp;
  }

  const int b = bh / 12, h = bh % 12;
  for (int rt = 0; rt < 2; ++rt)
    for (int r = 0; r < 4; ++r) {
      float inv = fast_rcp(O5[rt][r]);
      int tok = q0 + w * 32 + rt * 16 + g * 4 + r;
      for (int j = 0; j < 4; ++j) {
        int col = h * 64 + j * 16 + c;
        out[(size_t)(b * 2048 + tok) * 768 + col] = (bf16)(O[rt][j][r] * inv);
      }
    }
}

// ---------- launch ----------
extern "C" void kernel_launch(void* const* d_in, const int* in_sizes, int n_in,
                              void* d_out, int out_size, void* d_ws, size_t ws_size,
                              hipStream_t stream) {
  static const long expected[9] = {6291456, 768, 768, 1769472, 589824, 2359296,
                                   3072, 2359296, 768};
  long f = 1; bool found = false;
  for (long ff = 1; ff <= 4 && !found; ff *= 2)
    for (int i = 0; i < n_in; ++i)
      if ((long)in_sizes[i] == 6291456L * ff) { f = ff; found = true; break; }
  int idx[9]; bool used[32] = {false};
  for (int s = 0; s < 9; ++s) {
    idx[s] = -1;
    if (found)
      for (int i = 0; i < n_in; ++i)
        if (!used[i] && (long)in_sizes[i] == expected[s] * f) { idx[s] = i; used[i] = true; break; }
    if (idx[s] < 0) idx[s] = s;
  }
  const float* x    = (const float*)d_in[idx[0]];
  const float* ln_g = (const float*)d_in[idx[1]];
  const float* ln_b = (const float*)d_in[idx[2]];
  const float* wqkv = (const float*)d_in[idx[3]];
  const float* wao  = (const float*)d_in[idx[4]];
  const float* wi   = (const float*)d_in[idx[5]];
  const float* bi   = (const float*)d_in[idx[6]];
  const float* wo   = (const float*)d_in[idx[7]];
  const float* bo   = (const float*)d_in[idx[8]];

  char* ws = (char*)d_ws;
  bf16*  norm = (bf16*)(ws);
  bf16*  wtq  = (bf16*)(ws + 12582912);
  bf16*  at   = (bf16*)(ws + 12582912);
  bf16*  qb   = (bf16*)(ws + 25165824);
  bf16*  wta  = (bf16*)(ws + 25165824);
  bf16*  kb   = (bf16*)d_out;
  bf16*  vb   = (bf16*)((char*)d_out + 12582912);
  float* x1   = (float*)d_out;

  // MLP buffers: big path (full 8192x3072 hbuf, single x1 pass) needs 72.4 MB ws;
  // otherwise fall back to the proven 4-slice structure.
  const bool big = ws_size >= 72351744ULL;
  bf16* hbuf = (bf16*)(ws + 12582912);                       // 50.3 MB (big) / 12.6 MB
  bf16* wti  = big ? (bf16*)(ws + 62914560) : (bf16*)(ws + 26345472);
  bf16* wto  = big ? (bf16*)(ws + 67633152) : (bf16*)(ws + 31064064);

  ln_kernel<<<8192, 256, 0, stream>>>(x, ln_g, ln_b, norm);
  castT_kernel<1><<<dim3(36, 12), 256, 0, stream>>>(wqkv, wtq, 768, 2304);
  gemm_bt<128,0,0,0,0,1><<<dim3(18, 64), 256, 0, stream>>>(
      norm, wtq, 768, nullptr, nullptr, nullptr, qb, kb, vb, 8192, 2304, 768);
  attn_kernel<<<dim3(16, 48), 256, 0, stream>>>(qb, kb, vb, at);
  castT_kernel<0><<<dim3(12, 12), 256, 0, stream>>>(wao, wta, 768, 768);
  castT_kernel<0><<<dim3(48, 12), 256, 0, stream>>>(wi,  wti, 768, 3072);
  castT_kernel<0><<<dim3(12, 48), 256, 0, stream>>>(wo,  wto, 3072, 768);
  // x1 = x + at @ w_attn_out  (fp32 into d_out; k/v dead)
  gemm_bt<64,1,0,0,1,0><<<dim3(6, 128), 256, 0, stream>>>(
      at, wta, 768, x1, nullptr, x, nullptr, nullptr, nullptr, 8192, 768, 768);
  if (big) {
    // MLP (R9: MT=128, 64x64 per wave -> 1.5x less LDS-read per FLOP):
    // hbuf = gelu(norm@wi + bi) [8192x3072]; x1 += hbuf@wo + bo, K=3072
    gemm_bt<128,0,1,1,0,0><<<dim3(24, 64), 256, 0, stream>>>(
        norm, wti, 768, hbuf, bi, nullptr, nullptr, nullptr, nullptr, 8192, 3072, 768);
    gemm_bt<128,1,1,0,1,0><<<dim3(6, 64), 256, 0, stream>>>(
        hbuf, wto, 3072, x1, bo, x1, nullptr, nullptr, nullptr, 8192, 768, 3072);
  } else {
    // MLP: 4 x 768-wide FF slices (proven structure; x1 accumulates in place)
    for (int p = 0; p < 4; ++p) {
      gemm_bt<64,0,1,1,0,0><<<dim3(6, 128), 256, 0, stream>>>(
          norm, wti + (size_t)p * 768 * 768, 768, hbuf, bi + p * 768, nullptr,
          nullptr, nullptr, nullptr, 8192, 768, 768);
      if (p < 3)
        gemm_bt<64,1,0,0,1,0><<<dim3(6, 128), 256, 0, stream>>>(
            hbuf, wto + (size_t)p * 768, 3072, x1, nullptr, x1,
            nullptr, nullptr, nullptr, 8192, 768, 768);
      else
        gemm_bt<64,1,1,0,1,0><<<dim3(6, 128), 256, 0, stream>>>(
            hbuf, wto + (size_t)p * 768, 3072, x1, bo, x1,
            nullptr, nullptr, nullptr, 8192, 768, 768);
    }
  }
}

// Round 10
// 350.788 us; speedup vs baseline: 1.0682x; 1.0682x over previous
//
#include <hip/hip_runtime.h>
#include <math.h>

typedef __bf16 bf16;
typedef __bf16 bf16x8 __attribute__((ext_vector_type(8)));
typedef __bf16 bf16x4 __attribute__((ext_vector_type(4)));
typedef float  f32x4  __attribute__((ext_vector_type(4)));
typedef unsigned int u32;

#define MFMA16(a, b, c) __builtin_amdgcn_mfma_f32_16x16x32_bf16((a), (b), (c), 0, 0, 0)

__device__ __forceinline__ void async_copy16(const bf16* g, bf16* l) {
  __builtin_amdgcn_global_load_lds((const __attribute__((address_space(1))) void*)g,
                                   (__attribute__((address_space(3))) void*)l, 16, 0, 0);
}

__device__ __forceinline__ float fast_exp2(float x) {
#if __has_builtin(__builtin_amdgcn_exp2f)
  return __builtin_amdgcn_exp2f(x);
#else
  float r; asm("v_exp_f32 %0, %1" : "=v"(r) : "v"(x)); return r;
#endif
}

__device__ __forceinline__ float fast_rcp(float x) {
#if __has_builtin(__builtin_amdgcn_rcpf)
  return __builtin_amdgcn_rcpf(x);
#else
  float r; asm("v_rcp_f32 %0, %1" : "=v"(r) : "v"(x)); return r;
#endif
}

// erf via Abramowitz-Stegun 7.1.26 (|err| ~5e-7, far below bf16 eps); native exp2
__device__ __forceinline__ float fast_erff(float x) {
  float ax = fabsf(x);
  float t = fast_rcp(1.0f + 0.3275911f * ax);
  float p = t * (0.254829592f + t * (-0.284496736f + t * (1.421413741f +
            t * (-1.453152027f + t * 1.061405429f))));
  float e = fast_exp2(-ax * ax * 1.4426950408889634f);
  float r = 1.0f - p * e;
  return x < 0.0f ? -r : r;
}

// ---------- shared bodies ----------
__device__ __forceinline__ void ln_body(const float* __restrict__ x,
    const float* __restrict__ g, const float* __restrict__ b,
    bf16* __restrict__ nrm, int tok, int t, float* red) {
  const float* xr = x + (size_t)tok * 768;
  float v0 = xr[t], v1 = xr[t + 256], v2 = xr[t + 512];
  float s = v0 + v1 + v2, ss = v0 * v0 + v1 * v1 + v2 * v2;
  for (int off = 32; off; off >>= 1) {
    s += __shfl_down(s, off, 64); ss += __shfl_down(ss, off, 64);
  }
  if ((t & 63) == 0) { red[(t >> 6) * 2] = s; red[(t >> 6) * 2 + 1] = ss; }
  __syncthreads();
  s = red[0] + red[2] + red[4] + red[6];
  ss = red[1] + red[3] + red[5] + red[7];
  float mu = s * (1.f / 768.f);
  float rstd = rsqrtf(ss * (1.f / 768.f) - mu * mu + 1e-5f);
  bf16* o = nrm + (size_t)tok * 768;
  o[t]       = (bf16)((v0 - mu) * rstd * g[t]       + b[t]);
  o[t + 256] = (bf16)((v1 - mu) * rstd * g[t + 256] + b[t + 256]);
  o[t + 512] = (bf16)((v2 - mu) * rstd * g[t + 512] + b[t + 512]);
}

// cast+transpose 64x64 tile: out[n'][k] = (bf16)in[k][n]; perm remaps qkv cols
__device__ __forceinline__ void castT_body(const float* __restrict__ in,
    bf16* __restrict__ out, int K, int N, int perm, int n0, int k0, int t,
    float (*tile)[65]) {
  const int r = t >> 4, c4 = (t & 15) * 4;
  for (int it = 0; it < 4; ++it) {
    int row = r + it * 16;
    const float4 v = *(const float4*)(in + (size_t)(k0 + row) * N + n0 + c4);
    tile[row][c4] = v.x; tile[row][c4 + 1] = v.y;
    tile[row][c4 + 2] = v.z; tile[row][c4 + 3] = v.w;
  }
  __syncthreads();
  for (int it = 0; it < 4; ++it) {
    int row = r + it * 16;
    int n = n0 + row;
    if (perm) {
      int which = n / 768, rem = n - which * 768;
      int d = rem / 12, h = rem - d * 12;
      n = which * 768 + h * 64 + d;
    }
    bf16x4 v;
    for (int j = 0; j < 4; ++j) v[j] = (bf16)tile[c4 + j][row];
    *(bf16x4*)(out + (size_t)n * K + k0 + c4) = v;
  }
}

// ---------- merged prep: LN (8192 blocks) + all weight casts in one launch ------
// full=1: also cast wao/wi/wo (big path; wta relocated to the hbuf region which is
// written only later by MLP GEMM1). full=0: only ln + wqkv (fallback path).
__global__ __launch_bounds__(256) void prep_kernel(
    const float* __restrict__ x, const float* __restrict__ g,
    const float* __restrict__ b, bf16* __restrict__ nrm,
    const float* __restrict__ wqkv, bf16* __restrict__ wtq,
    const float* __restrict__ wao, bf16* __restrict__ wta,
    const float* __restrict__ wi, bf16* __restrict__ wti,
    const float* __restrict__ wo, bf16* __restrict__ wto, int full) {
  __shared__ float tile[64][65];
  const int t = threadIdx.x;
  int j = blockIdx.x;
  if (j < 8192) { ln_body(x, g, b, nrm, j, t, &tile[0][0]); return; }
  j -= 8192;
  if (j < 432) { castT_body(wqkv, wtq, 768, 2304, 1, (j % 36) * 64, (j / 36) * 64, t, tile); return; }
  if (!full) return;
  j -= 432;
  if (j < 144) { castT_body(wao, wta, 768, 768, 0, (j % 12) * 64, (j / 12) * 64, t, tile); return; }
  j -= 144;
  if (j < 576) { castT_body(wi, wti, 768, 3072, 0, (j % 48) * 64, (j / 48) * 64, t, tile); return; }
  j -= 576;
  castT_body(wo, wto, 3072, 768, 0, (j % 12) * 64, (j / 12) * 64, t, tile);
}

// standalone castT for the fallback path (original ordering/layout)
template <int PERM>
__global__ __launch_bounds__(256) void castT_kernel(const float* __restrict__ in,
    bf16* __restrict__ out, int K, int N) {
  __shared__ float tile[64][65];
  castT_body(in, out, K, N, PERM, blockIdx.x * 64, blockIdx.y * 64, threadIdx.x, tile);
}

// ---------- GEMM: C[M,N] = A[M,K]@Bt[N,K]^T; BK=64 (two 32-wide LDS halves) ----------
// R8 (proven): XOR-swizzled LDS sub-blocks (conflict-free ds_read_b128) +
// bijective XCD-chunked block remap (A row-panels pinned to one XCD's L2).
template <int MT, int RES, int BIAS, int GELU, int OUTF32, int SPLIT>
__global__ __launch_bounds__(256) void gemm_bt(
    const bf16* __restrict__ A, const bf16* __restrict__ Bt, int ldb,
    void* __restrict__ Cv, const float* __restrict__ bias, const float* __restrict__ res,
    bf16* __restrict__ qo, bf16* __restrict__ ko, bf16* __restrict__ vo,
    int M, int N, int K) {
  constexpr int NJ = (MT == 128) ? 4 : 2;
  constexpr int AH = MT * 32;              // elements per k-half of A
  __shared__ bf16 As[2 * AH];
  __shared__ bf16 Bs[2 * 4096];
  const int t = threadIdx.x;
  const int l = t & 63, w = t >> 6;
  const int lr = l >> 4, lc = l & 15;
  const int wm = (MT == 128) ? (w >> 1) : 0;
  const int wn = (MT == 128) ? (w & 1) : w;

  // XCD-chunked remap (physical id%8 = XCD; give each XCD a contiguous tile chunk)
  const int nwg = gridDim.x * gridDim.y;
  int bid = blockIdx.y * gridDim.x + blockIdx.x;
  if ((nwg & 7) == 0) bid = (bid & 7) * (nwg >> 3) + (bid >> 3);
  const int m0 = (bid / gridDim.x) * MT, n0 = (bid % gridDim.x) * 128;

  const int srow = t >> 2;                 // 0..63
  const int scol = ((t & 3) ^ ((t >> 3) & 3)) * 8;   // XOR-swizzled source sub-block
  const int sw   = (lr ^ ((lc >> 1) & 3)) * 8;       // matching read-side XOR
  const bf16* ga0 = A + (size_t)(m0 + srow) * K + scol;
  const bf16* ga1 = A + (size_t)(m0 + 64 + srow) * K + scol;   // MT==128 only
  const bf16* gb0 = Bt + (size_t)(n0 + srow) * ldb + scol;
  const bf16* gb1 = Bt + (size_t)(n0 + 64 + srow) * ldb + scol;

  f32x4 acc[4][NJ];
  for (int i = 0; i < 4; ++i)
    for (int j = 0; j < NJ; ++j) acc[i][j] = (f32x4){0.f, 0.f, 0.f, 0.f};

  for (int k0 = 0; k0 < K; k0 += 64) {
    async_copy16(ga0 + k0,      &As[w * 512]);
    async_copy16(ga0 + k0 + 32, &As[AH + w * 512]);
    if (MT == 128) {
      async_copy16(ga1 + k0,      &As[2048 + w * 512]);
      async_copy16(ga1 + k0 + 32, &As[AH + 2048 + w * 512]);
    }
    async_copy16(gb0 + k0,      &Bs[w * 512]);
    async_copy16(gb0 + k0 + 32, &Bs[4096 + w * 512]);
    async_copy16(gb1 + k0,      &Bs[2048 + w * 512]);
    async_copy16(gb1 + k0 + 32, &Bs[4096 + 2048 + w * 512]);
    __syncthreads();
    for (int h = 0; h < 2; ++h) {
      bf16x8 af[4], bfr[NJ];
      for (int i = 0; i < 4; ++i)
        af[i] = *(const bf16x8*)&As[h * AH + (wm * 64 + i * 16 + lc) * 32 + sw];
      for (int j = 0; j < NJ; ++j)
        bfr[j] = *(const bf16x8*)&Bs[h * 4096 + (wn * 16 * NJ + j * 16 + lc) * 32 + sw];
      for (int i = 0; i < 4; ++i)
        for (int j = 0; j < NJ; ++j)
          acc[i][j] = MFMA16(af[i], bfr[j], acc[i][j]);
    }
    __syncthreads();
  }

  const size_t Ns = (size_t)N;
  for (int i = 0; i < 4; ++i) {
    int rowb = m0 + wm * 64 + i * 16 + lr * 4;
    for (int j = 0; j < NJ; ++j) {
      int col = n0 + wn * 16 * NJ + j * 16 + lc;
      float bv = BIAS ? bias[col] : 0.f;
      for (int r = 0; r < 4; ++r) {
        int row = rowb + r;
        float vv = acc[i][j][r];
        if (BIAS) vv += bv;
        if (GELU) vv = 0.5f * vv * (1.f + fast_erff(vv * 0.70710678118654752f));
        if (RES)  vv += res[(size_t)row * Ns + col];
        if (SPLIT) {
          int which = col / 768;
          int rem = col - which * 768;
          int h = rem >> 6, d = rem & 63;
          int bb = row >> 11, tt = row & 2047;
          if (which == 2) {
            // V written directly in the attn LDS image (vT fused):
            // s = perm(key), pos = ((s>>3)^(d&7))*8 + (s&7)
            int T = tt >> 6, k2 = tt & 63;
            int sv = (k2 & 32) | ((k2 & 12) << 1) | ((k2 & 16) >> 2) | (k2 & 3);
            int pos = ((((sv >> 3) ^ (d & 7)) << 3) | (sv & 7));
            vo[(size_t)(bb * 12 + h) * 131072 + (size_t)T * 4096 + d * 64 + pos] = (bf16)vv;
          } else {
            // fold softmax scale (DIM^-0.5 * log2e) into Q; f32 mul before bf16 cast
            if (which == 0) vv *= 0.18033688011112042f;
            bf16* dst = which == 0 ? qo : ko;
            dst[((size_t)((bb * 12 + h) * 2048 + tt)) * 64 + d] = (bf16)vv;
          }
        } else if (OUTF32) {
          ((float*)Cv)[(size_t)row * Ns + col] = vv;
        } else {
          ((bf16*)Cv)[(size_t)row * Ns + col] = (bf16)vv;
        }
      }
    }
  }
}

// ---------- Flash attention v10: 4 waves x 32 q-rows -> 3 waves/SIMD -------------
// (proven R7) dbuf + counted vmcnt + native exp2 + folded scale + pre-transposed V
// + XCD swizzle + 768-block even grid; 3072 waves = 3 waves/SIMD.
__global__ __launch_bounds__(256) void attn_kernel(const bf16* __restrict__ q,
    const bf16* __restrict__ k, const bf16* __restrict__ v, bf16* __restrict__ out) {
  __shared__ bf16 Ks0[4096], Ks1[4096], Vs0[4096], Vs1[4096];  // 32 KB
  const int t = threadIdx.x;
  const int l = t & 63, w = t >> 6;                            // w in {0..3}
  const int g = l >> 4, c = l & 15;
  const int id = blockIdx.y * 16 + blockIdx.x;
  const int swz = (id & 7) * 96 + (id >> 3);
  const int bh = swz >> 4;
  const int q0 = (swz & 15) * 128;
  const size_t base = (size_t)bh * (2048 * 64);
  const int qr = q0 + w * 32;
  bf16x8 aq[2][2];
  for (int rt = 0; rt < 2; ++rt) {
    aq[rt][0] = *(const bf16x8*)(q + base + (size_t)(qr + rt * 16 + c) * 64 + 8 * g);
    aq[rt][1] = *(const bf16x8*)(q + base + (size_t)(qr + rt * 16 + c) * 64 + 32 + 8 * g);
  }
  f32x4 O[2][4], O5[2];
  for (int rt = 0; rt < 2; ++rt) {
    for (int j = 0; j < 4; ++j) O[rt][j] = (f32x4){0.f, 0.f, 0.f, 0.f};
    O5[rt] = (f32x4){0.f, 0.f, 0.f, 0.f};
  }
  bf16x8 ones;
  for (int i = 0; i < 8; ++i) ones[i] = (bf16)1.0f;

  const bf16* kt = k + base + (size_t)(8 * w + (l >> 3)) * 64 + ((l & 7) ^ (l >> 3)) * 8;
  const bf16* vt = v + base + w * 512 + l * 8;
  const int pk0 = (g ^ (c & 7)) * 8;
  const int pk1 = ((4 + g) ^ (c & 7)) * 8;

  auto stage = [&](const bf16* kp, const bf16* vp, bf16* KsD, bf16* VsD) {
    async_copy16(kp,        KsD + w * 512);
    async_copy16(kp + 2048, KsD + 2048 + w * 512);
    async_copy16(vp,        VsD + w * 512);
    async_copy16(vp + 2048, VsD + 2048 + w * 512);
  };

  auto compute = [&](const bf16* KsP, const bf16* VsP) {
    bf16x8 ap[2][2];
    #pragma unroll
    for (int m = 0; m < 4; ++m) {
      bf16x8 b0 = *(const bf16x8*)&KsP[(16 * m + c) * 64 + pk0];
      bf16x8 b1 = *(const bf16x8*)&KsP[(16 * m + c) * 64 + pk1];
      f32x4 Sm[2];
      #pragma unroll
      for (int rt = 0; rt < 2; ++rt) {
        f32x4 z = (f32x4){0.f, 0.f, 0.f, 0.f};
        z = MFMA16(b0, aq[rt][0], z);
        Sm[rt] = MFMA16(b1, aq[rt][1], z);
      }
      #pragma unroll
      for (int rt = 0; rt < 2; ++rt)
        #pragma unroll
        for (int r = 0; r < 4; ++r)
          ap[rt][m >> 1][(m & 1) * 4 + r] = (bf16)fast_exp2(Sm[rt][r]);
    }
    #pragma unroll
    for (int j = 0; j < 4; ++j) {
      bf16x8 bv0 = *(const bf16x8*)&VsP[(16 * j + c) * 64 + pk0];
      bf16x8 bv1 = *(const bf16x8*)&VsP[(16 * j + c) * 64 + pk1];
      #pragma unroll
      for (int rt = 0; rt < 2; ++rt) {
        O[rt][j] = MFMA16(ap[rt][0], bv0, O[rt][j]);
        O[rt][j] = MFMA16(ap[rt][1], bv1, O[rt][j]);
      }
    }
    #pragma unroll
    for (int rt = 0; rt < 2; ++rt) {
      O5[rt] = MFMA16(ap[rt][0], ones, O5[rt]);
      O5[rt] = MFMA16(ap[rt][1], ones, O5[rt]);
    }
  };

  stage(kt, vt, Ks0, Vs0);
  kt += 4096; vt += 4096;
  bf16 *ka = Ks0, *kb = Ks1, *va = Vs0, *vb = Vs1;
  for (int i = 0; i < 32; ++i) {
    __builtin_amdgcn_s_barrier();          // all waves done reading the other buffer
    if (i + 1 < 32) {
      stage(kt, vt, kb, vb);               // issue next tile (4 loads stay in flight)
      kt += 4096; vt += 4096;
      asm volatile("s_waitcnt vmcnt(4)" ::: "memory");   // current tile's loads done
    } else {
      asm volatile("s_waitcnt vmcnt(0)" ::: "memory");
    }
    __builtin_amdgcn_sched_barrier(0);
    __builtin_amdgcn_s_barrier();          // global visibility of current tile
    compute(ka, va);
    bf16* tmp;
    tmp = ka; ka = kb; kb = tmp;
    tmp = va; va = vb; vb = tmp;
  }

  const int b = bh / 12, h = bh % 12;
  for (int rt = 0; rt < 2; ++rt)
    for (int r = 0; r < 4; ++r) {
      float inv = fast_rcp(O5[rt][r]);
      int tok = q0 + w * 32 + rt * 16 + g * 4 + r;
      for (int j = 0; j < 4; ++j) {
        int col = h * 64 + j * 16 + c;
        out[(size_t)(b * 2048 + tok) * 768 + col] = (bf16)(O[rt][j][r] * inv);
      }
    }
}

// ---------- launch ----------
extern "C" void kernel_launch(void* const* d_in, const int* in_sizes, int n_in,
                              void* d_out, int out_size, void* d_ws, size_t ws_size,
                              hipStream_t stream) {
  static const long expected[9] = {6291456, 768, 768, 1769472, 589824, 2359296,
                                   3072, 2359296, 768};
  long f = 1; bool found = false;
  for (long ff = 1; ff <= 4 && !found; ff *= 2)
    for (int i = 0; i < n_in; ++i)
      if ((long)in_sizes[i] == 6291456L * ff) { f = ff; found = true; break; }
  int idx[9]; bool used[32] = {false};
  for (int s = 0; s < 9; ++s) {
    idx[s] = -1;
    if (found)
      for (int i = 0; i < n_in; ++i)
        if (!used[i] && (long)in_sizes[i] == expected[s] * f) { idx[s] = i; used[i] = true; break; }
    if (idx[s] < 0) idx[s] = s;
  }
  const float* x    = (const float*)d_in[idx[0]];
  const float* ln_g = (const float*)d_in[idx[1]];
  const float* ln_b = (const float*)d_in[idx[2]];
  const float* wqkv = (const float*)d_in[idx[3]];
  const float* wao  = (const float*)d_in[idx[4]];
  const float* wi   = (const float*)d_in[idx[5]];
  const float* bi   = (const float*)d_in[idx[6]];
  const float* wo   = (const float*)d_in[idx[7]];
  const float* bo   = (const float*)d_in[idx[8]];

  char* ws = (char*)d_ws;
  bf16*  norm = (bf16*)(ws);
  bf16*  wtq  = (bf16*)(ws + 12582912);
  bf16*  at   = (bf16*)(ws + 12582912);
  bf16*  qb   = (bf16*)(ws + 25165824);
  bf16*  kb   = (bf16*)d_out;
  bf16*  vb   = (bf16*)((char*)d_out + 12582912);
  float* x1   = (float*)d_out;

  // MLP buffers: big path (full 8192x3072 hbuf, single x1 pass) needs 72.4 MB ws;
  // otherwise fall back to the proven 4-slice structure.
  const bool big = ws_size >= 72351744ULL;
  bf16* hbuf = (bf16*)(ws + 12582912);                       // 50.3 MB (big) / 12.6 MB
  bf16* wti  = big ? (bf16*)(ws + 62914560) : (bf16*)(ws + 26345472);
  bf16* wto  = big ? (bf16*)(ws + 67633152) : (bf16*)(ws + 31064064);
  // wta: big path -> inside hbuf region (written upfront by prep, consumed by the
  // attn-out GEMM, clobbered only later by MLP GEMM1). fallback -> old alias of qb
  // (written after attn as before).
  bf16* wta  = big ? (bf16*)(ws + 37748736) : (bf16*)(ws + 25165824);

  if (big) {
    prep_kernel<<<9920, 256, 0, stream>>>(x, ln_g, ln_b, norm, wqkv, wtq,
                                          wao, wta, wi, wti, wo, wto, 1);
  } else {
    prep_kernel<<<8624, 256, 0, stream>>>(x, ln_g, ln_b, norm, wqkv, wtq,
                                          wao, wta, wi, wti, wo, wto, 0);
  }
  gemm_bt<128,0,0,0,0,1><<<dim3(18, 64), 256, 0, stream>>>(
      norm, wtq, 768, nullptr, nullptr, nullptr, qb, kb, vb, 8192, 2304, 768);
  attn_kernel<<<dim3(16, 48), 256, 0, stream>>>(qb, kb, vb, at);
  if (!big) {
    castT_kernel<0><<<dim3(12, 12), 256, 0, stream>>>(wao, wta, 768, 768);
    castT_kernel<0><<<dim3(48, 12), 256, 0, stream>>>(wi,  wti, 768, 3072);
    castT_kernel<0><<<dim3(12, 48), 256, 0, stream>>>(wo,  wto, 3072, 768);
  }
  // x1 = x + at @ w_attn_out  (fp32 into d_out; k/v dead)
  gemm_bt<64,1,0,0,1,0><<<dim3(6, 128), 256, 0, stream>>>(
      at, wta, 768, x1, nullptr, x, nullptr, nullptr, nullptr, 8192, 768, 768);
  if (big) {
    // MLP (R8-proven MT=64 shapes): hbuf = gelu(norm@wi + bi) [8192x3072];
    // x1 += hbuf@wo + bo with K=3072 (single fp32 write, no RMW slices)
    gemm_bt<64,0,1,1,0,0><<<dim3(24, 128), 256, 0, stream>>>(
        norm, wti, 768, hbuf, bi, nullptr, nullptr, nullptr, nullptr, 8192, 3072, 768);
    gemm_bt<64,1,1,0,1,0><<<dim3(6, 128), 256, 0, stream>>>(
        hbuf, wto, 3072, x1, bo, x1, nullptr, nullptr, nullptr, 8192, 768, 3072);
  } else {
    // MLP: 4 x 768-wide FF slices (proven structure; x1 accumulates in place)
    for (int p = 0; p < 4; ++p) {
      gemm_bt<64,0,1,1,0,0><<<dim3(6, 128), 256, 0, stream>>>(
          norm, wti + (size_t)p * 768 * 768, 768, hbuf, bi + p * 768, nullptr,
          nullptr, nullptr, nullptr, 8192, 768, 768);
      if (p < 3)
        gemm_bt<64,1,0,0,1,0><<<dim3(6, 128), 256, 0, stream>>>(
            hbuf, wto + (size_t)p * 768, 3072, x1, nullptr, x1,
            nullptr, nullptr, nullptr, 8192, 768, 768);
      else
        gemm_bt<64,1,1,0,1,0><<<dim3(6, 128), 256, 0, stream>>>(
            hbuf, wto + (size_t)p * 768, 3072, x1, bo, x1,
            nullptr, nullptr, nullptr, 8192, 768, 768);
    }
  }
}